// Round 8
// baseline (1191.647 us; speedup 1.0000x reference)
//
#include <hip/hip_runtime.h>
#include <hip/hip_bf16.h>

// R8: ablation round. prep_s + mlp_k1 + abl_g (GEMM-only x3) + abl_s
// (spline-only x3) + real spline_k2 (now with depth-2 W3T prefetch).
// abl kernels mirror K2's block/LDS config and write to dead ws scratch.

typedef short bf16x8 __attribute__((ext_vector_type(8)));
typedef float f32x4 __attribute__((ext_vector_type(4)));

#define KEEP(x) asm volatile("" :: "v"(x))

// ---- split-path ws layout ----
#define SW3T_B 0           // [4096][128] bf16 = 1048576
#define SW1T_B 1048576     // [128][192]  bf16 = 49152 (dead after K1 -> abl scratch)
#define SW2T_B 1097728     // [128][128]  bf16 = 32768
#define SB3P_B 1130496     // [4096] f32  = 16384
#define SH2_B  1146880     // [32768][128] bf16 = 8388608
#define SPLIT_WS_NEED 9535488ULL

// ---- fallback (R5) ws layout ----
#define FW3T_B 0
#define FW1T_B 917504
#define FW2T_B 966656
#define FB3P_B 999424

__device__ __forceinline__ float b2f(unsigned int u) {
    union { float f; unsigned int i; } v; v.i = u << 16; return v.f;
}
__device__ __forceinline__ unsigned short f2b(float f) {
    union { float f; unsigned int i; } v; v.f = f;
    unsigned int x = v.i;
    return (unsigned short)((x + 0x7fffu + ((x >> 16) & 1u)) >> 16);
}
__device__ __forceinline__ float splus(float x) {
    return __logf(1.0f + __expf(x));
}

// ================= split path =================

__global__ __launch_bounds__(256) void prep_s(
    const float* __restrict__ W1, const float* __restrict__ W2,
    const float* __restrict__ W3, const float* __restrict__ b3,
    char* __restrict__ ws)
{
    __shared__ __align__(16) float tbuf[4224];
    const int b = blockIdx.x, t = threadIdx.x;
    if (b < 128) {
        unsigned short* W3T = (unsigned short*)(ws + SW3T_B);
        const int c0 = b * 32;
        #pragma unroll
        for (int i = 0; i < 16; ++i) {
            int idx = i * 256 + t;
            int c = idx & 31, k = idx >> 5;
            unsigned int cg = (unsigned int)(c0 + c);
            unsigned int dim = cg >> 6, p = cg & 63u;
            float v = (p < 49u) ? W3[(size_t)k * 3136 + dim * 49 + p] : 0.0f;
            tbuf[c * 132 + k] = v;
        }
        __syncthreads();
        const int c = t >> 3, kg = (t & 7) * 16;
        unsigned int d[8];
        #pragma unroll
        for (int i = 0; i < 8; ++i) {
            unsigned int lo = f2b(tbuf[c * 132 + kg + 2 * i]);
            unsigned int hi = f2b(tbuf[c * 132 + kg + 2 * i + 1]);
            d[i] = lo | (hi << 16);
        }
        uint4* dst = (uint4*)(W3T + (size_t)(c0 + c) * 128 + kg);
        dst[0] = make_uint4(d[0], d[1], d[2], d[3]);
        dst[1] = make_uint4(d[4], d[5], d[6], d[7]);
    } else if (b < 138) {
        const float* src; unsigned short* dst; int Kdw, tk, tn;
        if (b < 134) { int lb = b - 128; src = W1; dst = (unsigned short*)(ws + SW1T_B); Kdw = 96; tk = lb % 3; tn = lb / 3; }
        else         { int lb = b - 134; src = W2; dst = (unsigned short*)(ws + SW2T_B); Kdw = 64; tk = lb & 1; tn = lb >> 1; }
        const int nl = t & 63, kq = t >> 6;
        #pragma unroll
        for (int i = 0; i < 16; ++i) {
            int kl = i * 4 + kq;
            tbuf[kl * 65 + nl] = src[(size_t)(tk * 64 + kl) * 128 + tn * 64 + nl];
        }
        __syncthreads();
        unsigned int* d32 = (unsigned int*)dst;
        const int kp = t & 31, nq = t >> 5;
        #pragma unroll
        for (int i = 0; i < 8; ++i) {
            int n = i * 8 + nq;
            unsigned int lo = f2b(tbuf[(2 * kp) * 65 + n]);
            unsigned int hi = f2b(tbuf[(2 * kp + 1) * 65 + n]);
            d32[(size_t)(tn * 64 + n) * Kdw + tk * 32 + kp] = lo | (hi << 16);
        }
    } else {
        int c = (b - 138) * 256 + t;
        unsigned int dim = (unsigned int)c >> 6, p = (unsigned int)c & 63u;
        float* b3p = (float*)(ws + SB3P_B);
        b3p[c] = (p < 49u) ? b3[dim * 49 + p] : 0.0f;
    }
}

__global__ __launch_bounds__(512) void mlp_k1(
    const float* __restrict__ u2, const float* __restrict__ cnd,
    const float* __restrict__ b1, const float* __restrict__ b2,
    char* __restrict__ ws)
{
    __shared__ __align__(16) char smem[43008];
    unsigned short* xb  = (unsigned short*)smem;            // [64][200]
    unsigned short* h1b = (unsigned short*)(smem + 25600);  // [64][136]
    unsigned short* h2b = (unsigned short*)smem;            // [64][144]
    const unsigned short* W1T = (const unsigned short*)(ws + SW1T_B);
    const unsigned short* W2T = (const unsigned short*)(ws + SW2T_B);
    unsigned short* H2 = (unsigned short*)(ws + SH2_B);

    const int t = threadIdx.x;
    const int row0 = blockIdx.x * 64;
    const int w = t >> 6, lane = t & 63;
    const int l15 = lane & 15, lg = lane >> 4;

    {
        const float2* u2v = (const float2*)(u2 + (size_t)row0 * 64);
        #pragma unroll
        for (int p = 0; p < 4; ++p) {
            int idx = t + p * 512;
            int r = idx >> 5, c2 = idx & 31;
            float2 v = u2v[idx];
            *(unsigned int*)((char*)xb + r * 400 + c2 * 4) =
                (unsigned int)f2b(v.x) | ((unsigned int)f2b(v.y) << 16);
        }
        const float2* cdv = (const float2*)(cnd + (size_t)row0 * 128);
        #pragma unroll
        for (int p = 0; p < 8; ++p) {
            int idx = t + p * 512;
            int r = idx >> 6, c2 = idx & 63;
            float2 v = cdv[idx];
            *(unsigned int*)((char*)xb + r * 400 + 128 + c2 * 4) =
                (unsigned int)f2b(v.x) | ((unsigned int)f2b(v.y) << 16);
        }
    }
    __syncthreads();

    {
        const int mt = w >> 1;
        bf16x8 af[6];
        #pragma unroll
        for (int kg = 0; kg < 6; ++kg)
            af[kg] = *(const bf16x8*)((char*)xb + (mt * 16 + l15) * 400 + kg * 64 + lg * 16);
        #pragma unroll
        for (int ni = 0; ni < 4; ++ni) {
            int nt = (w & 1) + ni * 2;
            int j = nt * 16 + l15;
            f32x4 acc = {0.f, 0.f, 0.f, 0.f};
            #pragma unroll
            for (int kg = 0; kg < 6; ++kg) {
                bf16x8 bf = *(const bf16x8*)(W1T + (size_t)j * 192 + kg * 32 + lg * 8);
                acc = __builtin_amdgcn_mfma_f32_16x16x32_bf16(af[kg], bf, acc, 0, 0, 0);
            }
            float bj = b1[j];
            #pragma unroll
            for (int r = 0; r < 4; ++r)
                h1b[(mt * 16 + lg * 4 + r) * 136 + j] = f2b(fmaxf(acc[r] + bj, 0.f));
        }
    }
    __syncthreads();

    {
        const int mt = w >> 1;
        bf16x8 af[4];
        #pragma unroll
        for (int kg = 0; kg < 4; ++kg)
            af[kg] = *(const bf16x8*)((char*)h1b + (mt * 16 + l15) * 272 + kg * 64 + lg * 16);
        #pragma unroll
        for (int ni = 0; ni < 4; ++ni) {
            int nt = (w & 1) + ni * 2;
            int j = nt * 16 + l15;
            f32x4 acc = {0.f, 0.f, 0.f, 0.f};
            #pragma unroll
            for (int kg = 0; kg < 4; ++kg) {
                bf16x8 bf = *(const bf16x8*)(W2T + (size_t)j * 128 + kg * 32 + lg * 8);
                acc = __builtin_amdgcn_mfma_f32_16x16x32_bf16(af[kg], bf, acc, 0, 0, 0);
            }
            float bj = b2[j];
            #pragma unroll
            for (int r = 0; r < 4; ++r)
                h2b[(mt * 16 + lg * 4 + r) * 144 + j] = f2b(fmaxf(acc[r] + bj, 0.f));
        }
    }
    __syncthreads();

    {
        int r = t >> 3, cq = t & 7;
        uint4 v0 = *(const uint4*)((char*)h2b + r * 288 + cq * 32);
        uint4 v1 = *(const uint4*)((char*)h2b + r * 288 + cq * 32 + 16);
        uint4* dst = (uint4*)(H2 + ((size_t)(row0 + r) * 128 + cq * 16));
        dst[0] = v0;
        dst[1] = v1;
    }
}

// ---- shared GEMM-chunk macro body (depth-2 prefetch) used by K2 and abl_g ----
#define GEMM_CHUNK(DC)                                                          \
    {                                                                           \
        const int cbase = (DC) * 512 + ng * 256 + l15;                          \
        bf16x8 bfb[2][4];                                                       \
        _Pragma("unroll")                                                       \
        for (int kg = 0; kg < 4; ++kg) {                                        \
            bfb[0][kg] = *(const bf16x8*)(W3T + (size_t)cbase * 128 + kg * 32 + lg * 8);        \
            bfb[1][kg] = *(const bf16x8*)(W3T + (size_t)(cbase + 16) * 128 + kg * 32 + lg * 8); \
        }                                                                       \
        _Pragma("unroll")                                                       \
        for (int i = 0; i < 16; ++i) {                                          \
            int colg = cbase + i * 16;                                          \
            float bj = b3p[colg];                                               \
            f32x4 acc0 = {0.f, 0.f, 0.f, 0.f}, acc1 = {0.f, 0.f, 0.f, 0.f};     \
            acc0 = __builtin_amdgcn_mfma_f32_16x16x32_bf16(a3[0], bfb[i & 1][0], acc0, 0, 0, 0); \
            acc1 = __builtin_amdgcn_mfma_f32_16x16x32_bf16(a3[1], bfb[i & 1][1], acc1, 0, 0, 0); \
            acc0 = __builtin_amdgcn_mfma_f32_16x16x32_bf16(a3[2], bfb[i & 1][2], acc0, 0, 0, 0); \
            acc1 = __builtin_amdgcn_mfma_f32_16x16x32_bf16(a3[3], bfb[i & 1][3], acc1, 0, 0, 0); \
            if (i + 2 < 16) {                                                   \
                _Pragma("unroll")                                               \
                for (int kg = 0; kg < 4; ++kg)                                  \
                    bfb[i & 1][kg] = *(const bf16x8*)(W3T + (size_t)(colg + 32) * 128 + kg * 32 + lg * 8); \
            }                                                                   \
            int c = ng * 256 + i * 16 + l15;                                    \
            int coff = ((c >> 3) & 7) * 64 + (c >> 6) * 8 + (c & 7);            \
            _Pragma("unroll")                                                   \
            for (int r = 0; r < 4; ++r)                                         \
                rawb[(mt3 * 16 + lg * 4 + r) * 520 + coff] = f2b(acc0[r] + acc1[r] + bj); \
        }                                                                       \
    }

// ---- ablation: GEMM phase only, 3 passes ----
__global__ __launch_bounds__(512) void abl_g(
    const float* __restrict__ u1, char* __restrict__ ws)
{
    __shared__ __align__(16) unsigned short rawb[64 * 520];
    const unsigned short* W3T = (const unsigned short*)(ws + SW3T_B);
    const float* b3p = (const float*)(ws + SB3P_B);
    const unsigned short* H2 = (const unsigned short*)(ws + SH2_B);
    float* dmy = (float*)(ws + SW1T_B);

    const int t = threadIdx.x;
    const int row0 = blockIdx.x * 64;
    const int w = t >> 6, lane = t & 63;
    const int l15 = lane & 15, lg = lane >> 4;
    const int mt3 = w & 3, ng = w >> 2;
    const int lrow = t >> 3, dsl = t & 7;

    bf16x8 a3[4];
    #pragma unroll
    for (int kg = 0; kg < 4; ++kg)
        a3[kg] = *(const bf16x8*)(H2 + ((size_t)(row0 + mt3 * 16 + l15) * 128 + kg * 32 + lg * 8));

    float sink = 0.f;
    #pragma unroll 1
    for (int pass = 0; pass < 3; ++pass) {
        #pragma unroll 1
        for (int dc = 0; dc < 8; ++dc) {
            const float tv = u1[(size_t)(row0 + lrow) * 64 + dc * 8 + dsl];
            KEEP(tv);
            GEMM_CHUNK(dc)
            __syncthreads();
            uint4 probe = *(const uint4*)(rawb + lrow * 520 + dsl * 8);
            KEEP(probe.x); KEEP(probe.y); KEEP(probe.z); KEEP(probe.w);
            sink += tv;
            __syncthreads();
        }
    }
    dmy[((unsigned)(t * 2654435761u) >> 20) & 4095] = sink;
}

// ---- ablation: spline phase only, 3 passes ----
__global__ __launch_bounds__(512) void abl_s(
    const float* __restrict__ u1, char* __restrict__ ws)
{
    __shared__ __align__(16) unsigned short rawb[64 * 520];
    float* dmy = (float*)(ws + SW1T_B);

    const int t = threadIdx.x;
    const int row0 = blockIdx.x * 64;
    const int lrow = t >> 3, dsl = t & 7;

    for (int idx = t; idx < 64 * 520; idx += 512)
        rawb[idx] = f2b(((float)((idx * 1103515245u >> 16) & 1023)) * 0.004f - 2.0f);
    __syncthreads();

    const float XS = logf(expm1f(0.625f));
    const float DS = logf(expm1f(1.0f));
    float lja = 0.f;

    #pragma unroll 1
    for (int pass = 0; pass < 3; ++pass) {
        #pragma unroll 1
        for (int dc = 0; dc < 8; ++dc) {
            const float tv = u1[(size_t)(row0 + lrow) * 64 + dc * 8 + dsl];
            __syncthreads();
            {
                union { uint4 q[7]; unsigned short s[56]; } P;
                const uint4* pq = (const uint4*)(rawb + lrow * 520 + dsl * 8);
                #pragma unroll
                for (int i = 0; i < 7; ++i) P.q[i] = pq[i * 8];

                const float left   = b2f(P.s[0]) - 5.0f;
                const float bottom = b2f(P.s[1]) - 5.0f;
                float wv[16], hv[16];
                float wsum = 0.f, hsum = 0.f;
                #pragma unroll
                for (int i = 0; i < 16; ++i) { wv[i] = splus(b2f(P.s[2 + i])  + XS); wsum += wv[i]; }
                #pragma unroll
                for (int i = 0; i < 16; ++i) { hv[i] = splus(b2f(P.s[18 + i]) + XS); hsum += hv[i]; }
                const float scale = hsum / wsum;
                float kx = left; int cnt = (kx < tv) ? 1 : 0;
                #pragma unroll
                for (int i = 0; i < 16; ++i) { kx += wv[i]; cnt += (kx < tv) ? 1 : 0; }
                const bool indom = (left < tv) && (tv <= kx);
                const int hi = min(max(cnt, 1), 16);
                const int lo = hi - 1;
                float xk = 0.f, xkp = 0.f, yk = 0.f, ykp = 0.f;
                float cx = left, cy = bottom;
                #pragma unroll
                for (int i = 0; i < 16; ++i) {
                    float nx = cx + wv[i], ny = cy + hv[i];
                    if (i == lo) { xk = cx; xkp = nx; yk = cy; ykp = ny; }
                    cx = nx; cy = ny;
                }
                const int pl = 33 + lo, ph = 33 + hi;
                const float dk  = (lo == 0)
                    ? scale : splus(b2f(rawb[lrow * 520 + (pl >> 3) * 64 + dsl * 8 + (pl & 7)]) + DS);
                const float dkp = (hi == 16)
                    ? scale : splus(b2f(rawb[lrow * 520 + (ph >> 3) * 64 + dsl * 8 + (ph & 7)]) + DS);
                const float dxk = xkp - xk, dyk = ykp - yk;
                const float sk = dyk / dxk;
                float xi = (tv - xk) / dxk;
                xi = fminf(fmaxf(xi, 0.f), 1.f);
                const float om = 1.f - xi;
                const float num = dyk * (sk * xi * xi + dk * xi * om);
                const float den = sk + (dkp + dk - 2.f * sk) * xi * om;
                const float resin = yk + num / den;
                const float jn = sk * sk * (dkp * xi * xi + 2.f * sk * xi * om + dk * om * om);
                const float ljin = __logf(jn + 1e-10f) - __logf(den * den + 1e-10f);
                const float resout = scale * tv + (bottom - scale * left);
                const float ljout = __logf(scale + 1e-10f);
                dmy[((unsigned)((t + dc * 512) * 2654435761u) >> 20) & 4095] = indom ? resin : resout;
                lja += indom ? ljin : ljout;
            }
            __syncthreads();
        }
    }
    float lj = lja;
    lj += __shfl_xor(lj, 1, 64);
    lj += __shfl_xor(lj, 2, 64);
    lj += __shfl_xor(lj, 4, 64);
    dmy[((unsigned)(t * 40503u) >> 4) & 4095] = lj;
}

// ---- real K2: GEMM3 + spline (depth-2 prefetch) ----
__global__ __launch_bounds__(512) void spline_k2(
    const float* __restrict__ u1, const char* __restrict__ ws,
    float* __restrict__ out)
{
    __shared__ __align__(16) unsigned short rawb[64 * 520];
    const unsigned short* W3T = (const unsigned short*)(ws + SW3T_B);
    const float* b3p = (const float*)(ws + SB3P_B);
    const unsigned short* H2 = (const unsigned short*)(ws + SH2_B);

    const int t = threadIdx.x;
    const int row0 = blockIdx.x * 64;
    const int w = t >> 6, lane = t & 63;
    const int l15 = lane & 15, lg = lane >> 4;
    const int mt3 = w & 3, ng = w >> 2;
    const int lrow = t >> 3, dsl = t & 7;

    bf16x8 a3[4];
    #pragma unroll
    for (int kg = 0; kg < 4; ++kg)
        a3[kg] = *(const bf16x8*)(H2 + ((size_t)(row0 + mt3 * 16 + l15) * 128 + kg * 32 + lg * 8));

    const float XS = logf(expm1f(0.625f));
    const float DS = logf(expm1f(1.0f));
    float lja = 0.f;

    #pragma unroll 1
    for (int dc = 0; dc < 8; ++dc) {
        const float tv = u1[(size_t)(row0 + lrow) * 64 + dc * 8 + dsl];
        GEMM_CHUNK(dc)
        __syncthreads();
        {
            union { uint4 q[7]; unsigned short s[56]; } P;
            const uint4* pq = (const uint4*)(rawb + lrow * 520 + dsl * 8);
            #pragma unroll
            for (int i = 0; i < 7; ++i) P.q[i] = pq[i * 8];

            const float left   = b2f(P.s[0]) - 5.0f;
            const float bottom = b2f(P.s[1]) - 5.0f;
            float wv[16], hv[16];
            float wsum = 0.f, hsum = 0.f;
            #pragma unroll
            for (int i = 0; i < 16; ++i) { wv[i] = splus(b2f(P.s[2 + i])  + XS); wsum += wv[i]; }
            #pragma unroll
            for (int i = 0; i < 16; ++i) { hv[i] = splus(b2f(P.s[18 + i]) + XS); hsum += hv[i]; }
            const float scale = hsum / wsum;
            float kx = left; int cnt = (kx < tv) ? 1 : 0;
            #pragma unroll
            for (int i = 0; i < 16; ++i) { kx += wv[i]; cnt += (kx < tv) ? 1 : 0; }
            const bool indom = (left < tv) && (tv <= kx);
            const int hi = min(max(cnt, 1), 16);
            const int lo = hi - 1;
            float xk = 0.f, xkp = 0.f, yk = 0.f, ykp = 0.f;
            float cx = left, cy = bottom;
            #pragma unroll
            for (int i = 0; i < 16; ++i) {
                float nx = cx + wv[i], ny = cy + hv[i];
                if (i == lo) { xk = cx; xkp = nx; yk = cy; ykp = ny; }
                cx = nx; cy = ny;
            }
            const int pl = 33 + lo, ph = 33 + hi;
            const float dk  = (lo == 0)
                ? scale : splus(b2f(rawb[lrow * 520 + (pl >> 3) * 64 + dsl * 8 + (pl & 7)]) + DS);
            const float dkp = (hi == 16)
                ? scale : splus(b2f(rawb[lrow * 520 + (ph >> 3) * 64 + dsl * 8 + (ph & 7)]) + DS);
            const float dxk = xkp - xk, dyk = ykp - yk;
            const float sk = dyk / dxk;
            float xi = (tv - xk) / dxk;
            xi = fminf(fmaxf(xi, 0.f), 1.f);
            const float om = 1.f - xi;
            const float num = dyk * (sk * xi * xi + dk * xi * om);
            const float den = sk + (dkp + dk - 2.f * sk) * xi * om;
            const float resin = yk + num / den;
            const float jn = sk * sk * (dkp * xi * xi + 2.f * sk * xi * om + dk * om * om);
            const float ljin = __logf(jn + 1e-10f) - __logf(den * den + 1e-10f);
            const float resout = scale * tv + (bottom - scale * left);
            const float ljout = __logf(scale + 1e-10f);
            out[(size_t)(row0 + lrow) * 64 + dc * 8 + dsl] = indom ? resin : resout;
            lja += indom ? ljin : ljout;
        }
        __syncthreads();
    }

    float lj = lja;
    lj += __shfl_xor(lj, 1, 64);
    lj += __shfl_xor(lj, 2, 64);
    lj += __shfl_xor(lj, 4, 64);
    if (dsl == 0) out[(size_t)32768 * 64 + row0 + lrow] = lj;
}

// ================= fallback path (R5, verbatim) =================

__global__ __launch_bounds__(256) void prep_f(
    const float* __restrict__ W1, const float* __restrict__ W2,
    const float* __restrict__ W3, const float* __restrict__ b3,
    char* __restrict__ ws)
{
    __shared__ __align__(16) float tbuf[4224];
    const int b = blockIdx.x, t = threadIdx.x;
    if (b < 112) {
        unsigned short* W3T = (unsigned short*)(ws + FW3T_B);
        const int c0 = b * 32;
        #pragma unroll
        for (int i = 0; i < 16; ++i) {
            int idx = i * 256 + t;
            int c = idx & 31, k = idx >> 5;
            unsigned int cg = (unsigned int)(c0 + c);
            unsigned int dim = cg / 56u, p = cg % 56u;
            float v = (p < 49u) ? W3[(size_t)k * 3136 + dim * 49 + p] : 0.0f;
            tbuf[c * 132 + k] = v;
        }
        __syncthreads();
        const int c = t >> 3, kg = (t & 7) * 16;
        unsigned int d[8];
        #pragma unroll
        for (int i = 0; i < 8; ++i) {
            unsigned int lo = f2b(tbuf[c * 132 + kg + 2 * i]);
            unsigned int hi = f2b(tbuf[c * 132 + kg + 2 * i + 1]);
            d[i] = lo | (hi << 16);
        }
        uint4* dst = (uint4*)(W3T + (size_t)(c0 + c) * 128 + kg);
        dst[0] = make_uint4(d[0], d[1], d[2], d[3]);
        dst[1] = make_uint4(d[4], d[5], d[6], d[7]);
    } else if (b < 122) {
        const float* src; unsigned short* dst; int Kdw, tk, tn;
        if (b < 118) { int lb = b - 112; src = W1; dst = (unsigned short*)(ws + FW1T_B); Kdw = 96; tk = lb % 3; tn = lb / 3; }
        else         { int lb = b - 118; src = W2; dst = (unsigned short*)(ws + FW2T_B); Kdw = 64; tk = lb & 1; tn = lb >> 1; }
        const int nl = t & 63, kq = t >> 6;
        #pragma unroll
        for (int i = 0; i < 16; ++i) {
            int kl = i * 4 + kq;
            tbuf[kl * 65 + nl] = src[(size_t)(tk * 64 + kl) * 128 + tn * 64 + nl];
        }
        __syncthreads();
        unsigned int* d32 = (unsigned int*)dst;
        const int kp = t & 31, nq = t >> 5;
        #pragma unroll
        for (int i = 0; i < 8; ++i) {
            int n = i * 8 + nq;
            unsigned int lo = f2b(tbuf[(2 * kp) * 65 + n]);
            unsigned int hi = f2b(tbuf[(2 * kp + 1) * 65 + n]);
            d32[(size_t)(tn * 64 + n) * Kdw + tk * 32 + kp] = lo | (hi << 16);
        }
    } else {
        int c = (b - 122) * 256 + t;
        unsigned int dim = (unsigned int)c / 56u, p = (unsigned int)c % 56u;
        float* b3p = (float*)(ws + FB3P_B);
        b3p[c] = (p < 49u) ? b3[dim * 49 + p] : 0.0f;
    }
}

__global__ __launch_bounds__(512, 4) void spline_mega(
    const float* __restrict__ u1, const float* __restrict__ u2,
    const float* __restrict__ cnd, const float* __restrict__ b1,
    const float* __restrict__ b2, const char* __restrict__ ws,
    float* __restrict__ out)
{
    __shared__ __align__(16) char smem[75776];
    unsigned short* h2b  = (unsigned short*)smem;
    unsigned short* xb   = (unsigned short*)(smem + 17408);
    unsigned short* h1b  = (unsigned short*)(smem + 43008);
    unsigned short* rawb = (unsigned short*)(smem + 17408);
    const unsigned short* W3T = (const unsigned short*)(ws + FW3T_B);
    const unsigned short* W1T = (const unsigned short*)(ws + FW1T_B);
    const unsigned short* W2T = (const unsigned short*)(ws + FW2T_B);
    const float* b3p = (const float*)(ws + FB3P_B);

    const int t = threadIdx.x;
    const int row0 = blockIdx.x * 64;
    const int w = t >> 6, lane = t & 63;
    const int l15 = lane & 15, lg = lane >> 4;

    {
        const float2* u2v = (const float2*)(u2 + (size_t)row0 * 64);
        #pragma unroll
        for (int p = 0; p < 4; ++p) {
            int idx = t + p * 512;
            int r = idx >> 5, c2 = idx & 31;
            float2 v = u2v[idx];
            *(unsigned int*)((char*)xb + r * 400 + c2 * 4) =
                (unsigned int)f2b(v.x) | ((unsigned int)f2b(v.y) << 16);
        }
        const float2* cdv = (const float2*)(cnd + (size_t)row0 * 128);
        #pragma unroll
        for (int p = 0; p < 8; ++p) {
            int idx = t + p * 512;
            int r = idx >> 6, c2 = idx & 63;
            float2 v = cdv[idx];
            *(unsigned int*)((char*)xb + r * 400 + 128 + c2 * 4) =
                (unsigned int)f2b(v.x) | ((unsigned int)f2b(v.y) << 16);
        }
    }
    __syncthreads();

    {
        const int mt = w >> 1;
        bf16x8 af[6];
        #pragma unroll
        for (int kg = 0; kg < 6; ++kg)
            af[kg] = *(const bf16x8*)((char*)xb + (mt * 16 + l15) * 400 + kg * 64 + lg * 16);
        #pragma unroll
        for (int ni = 0; ni < 4; ++ni) {
            int nt = (w & 1) + ni * 2;
            int j = nt * 16 + l15;
            f32x4 acc = {0.f, 0.f, 0.f, 0.f};
            #pragma unroll
            for (int kg = 0; kg < 6; ++kg) {
                bf16x8 bf = *(const bf16x8*)(W1T + (size_t)j * 192 + kg * 32 + lg * 8);
                acc = __builtin_amdgcn_mfma_f32_16x16x32_bf16(af[kg], bf, acc, 0, 0, 0);
            }
            float bj = b1[j];
            #pragma unroll
            for (int r = 0; r < 4; ++r)
                h1b[(mt * 16 + lg * 4 + r) * 136 + j] = f2b(fmaxf(acc[r] + bj, 0.f));
        }
    }
    __syncthreads();

    {
        const int mt = w >> 1;
        bf16x8 af[4];
        #pragma unroll
        for (int kg = 0; kg < 4; ++kg)
            af[kg] = *(const bf16x8*)((char*)h1b + (mt * 16 + l15) * 272 + kg * 64 + lg * 16);
        #pragma unroll
        for (int ni = 0; ni < 4; ++ni) {
            int nt = (w & 1) + ni * 2;
            int j = nt * 16 + l15;
            f32x4 acc = {0.f, 0.f, 0.f, 0.f};
            #pragma unroll
            for (int kg = 0; kg < 4; ++kg) {
                bf16x8 bf = *(const bf16x8*)(W2T + (size_t)j * 128 + kg * 32 + lg * 8);
                acc = __builtin_amdgcn_mfma_f32_16x16x32_bf16(af[kg], bf, acc, 0, 0, 0);
            }
            float bj = b2[j];
            #pragma unroll
            for (int r = 0; r < 4; ++r)
                h2b[(mt * 16 + lg * 4 + r) * 136 + j] = f2b(fmaxf(acc[r] + bj, 0.f));
        }
    }
    __syncthreads();

    const float XS = logf(expm1f(0.625f));
    const float DS = logf(expm1f(1.0f));

    const int mt3 = w & 3, ng = w >> 2;
    bf16x8 a3[4];
    #pragma unroll
    for (int kg = 0; kg < 4; ++kg)
        a3[kg] = *(const bf16x8*)((char*)h2b + (mt3 * 16 + l15) * 272 + kg * 64 + lg * 16);
    const int lrow = t >> 3, dsl = t & 7;
    float lja = 0.f;

    for (int dc = 0; dc < 8; ++dc) {
        const float tv = u1[(size_t)(row0 + lrow) * 64 + dc * 8 + dsl];
        {
            bf16x8 bf0[4];
            {
                int colg = dc * 448 + ng * 16 + l15;
                #pragma unroll
                for (int kg = 0; kg < 4; ++kg)
                    bf0[kg] = *(const bf16x8*)(W3T + (size_t)colg * 128 + kg * 32 + lg * 8);
            }
            for (int nt = ng; nt < 28; nt += 2) {
                int colg = dc * 448 + nt * 16 + l15;
                bf16x8 bf1[4];
                if (nt + 2 < 28) {
                    #pragma unroll
                    for (int kg = 0; kg < 4; ++kg)
                        bf1[kg] = *(const bf16x8*)(W3T + (size_t)(colg + 32) * 128 + kg * 32 + lg * 8);
                }
                float bj = b3p[colg];
                f32x4 acc0 = {0.f, 0.f, 0.f, 0.f}, acc1 = {0.f, 0.f, 0.f, 0.f};
                acc0 = __builtin_amdgcn_mfma_f32_16x16x32_bf16(a3[0], bf0[0], acc0, 0, 0, 0);
                acc1 = __builtin_amdgcn_mfma_f32_16x16x32_bf16(a3[1], bf0[1], acc1, 0, 0, 0);
                acc0 = __builtin_amdgcn_mfma_f32_16x16x32_bf16(a3[2], bf0[2], acc0, 0, 0, 0);
                acc1 = __builtin_amdgcn_mfma_f32_16x16x32_bf16(a3[3], bf0[3], acc1, 0, 0, 0);
                #pragma unroll
                for (int r = 0; r < 4; ++r)
                    rawb[(mt3 * 16 + lg * 4 + r) * 456 + nt * 16 + l15] =
                        f2b(acc0[r] + acc1[r] + bj);
                #pragma unroll
                for (int kg = 0; kg < 4; ++kg) bf0[kg] = bf1[kg];
            }
        }
        __syncthreads();
        {
            union { uint4 q[7]; unsigned short s[56]; } P;
            const uint4* pq = (const uint4*)(rawb + lrow * 456 + dsl * 56);
            #pragma unroll
            for (int i = 0; i < 7; ++i) P.q[i] = pq[i];

            const float left   = b2f(P.s[0]) - 5.0f;
            const float bottom = b2f(P.s[1]) - 5.0f;
            float wv[16], hv[16];
            float wsum = 0.f, hsum = 0.f;
            #pragma unroll
            for (int i = 0; i < 16; ++i) { wv[i] = splus(b2f(P.s[2 + i])  + XS); wsum += wv[i]; }
            #pragma unroll
            for (int i = 0; i < 16; ++i) { hv[i] = splus(b2f(P.s[18 + i]) + XS); hsum += hv[i]; }
            const float scale = hsum / wsum;
            float kx = left; int cnt = (kx < tv) ? 1 : 0;
            #pragma unroll
            for (int i = 0; i < 16; ++i) { kx += wv[i]; cnt += (kx < tv) ? 1 : 0; }
            const bool indom = (left < tv) && (tv <= kx);
            const int hi = min(max(cnt, 1), 16);
            const int lo = hi - 1;
            float xk = 0.f, xkp = 0.f, yk = 0.f, ykp = 0.f;
            float cx = left, cy = bottom;
            #pragma unroll
            for (int i = 0; i < 16; ++i) {
                float nx = cx + wv[i], ny = cy + hv[i];
                if (i == lo) { xk = cx; xkp = nx; yk = cy; ykp = ny; }
                cx = nx; cy = ny;
            }
            const unsigned short* prd = rawb + lrow * 456 + dsl * 56;
            const float dk  = (lo == 0)  ? scale : splus(b2f(prd[33 + lo]) + DS);
            const float dkp = (hi == 16) ? scale : splus(b2f(prd[33 + hi]) + DS);
            const float dxk = xkp - xk, dyk = ykp - yk;
            const float sk = dyk / dxk;
            float xi = (tv - xk) / dxk;
            xi = fminf(fmaxf(xi, 0.f), 1.f);
            const float om = 1.f - xi;
            const float num = dyk * (sk * xi * xi + dk * xi * om);
            const float den = sk + (dkp + dk - 2.f * sk) * xi * om;
            const float resin = yk + num / den;
            const float jn = sk * sk * (dkp * xi * xi + 2.f * sk * xi * om + dk * om * om);
            const float ljin = __logf(jn + 1e-10f) - __logf(den * den + 1e-10f);
            const float resout = scale * tv + (bottom - scale * left);
            const float ljout = __logf(scale + 1e-10f);
            out[(size_t)(row0 + lrow) * 64 + dc * 8 + dsl] = indom ? resin : resout;
            lja += indom ? ljin : ljout;
        }
        __syncthreads();
    }

    float lj = lja;
    lj += __shfl_xor(lj, 1, 64);
    lj += __shfl_xor(lj, 2, 64);
    lj += __shfl_xor(lj, 4, 64);
    if (dsl == 0) out[(size_t)32768 * 64 + row0 + lrow] = lj;
}

extern "C" void kernel_launch(void* const* d_in, const int* in_sizes, int n_in,
                              void* d_out, int out_size, void* d_ws, size_t ws_size,
                              hipStream_t stream) {
    const float* u1 = (const float*)d_in[0];
    const float* u2 = (const float*)d_in[1];
    const float* cd = (const float*)d_in[2];
    const float* W1 = (const float*)d_in[3];
    const float* b1 = (const float*)d_in[4];
    const float* W2 = (const float*)d_in[5];
    const float* b2 = (const float*)d_in[6];
    const float* W3 = (const float*)d_in[7];
    const float* b3 = (const float*)d_in[8];
    char* ws = (char*)d_ws;
    if (ws_size >= SPLIT_WS_NEED) {
        prep_s<<<154, 256, 0, stream>>>(W1, W2, W3, b3, ws);
        mlp_k1<<<512, 512, 0, stream>>>(u2, cd, b1, b2, ws);
        abl_g<<<512, 512, 0, stream>>>(u1, ws);
        abl_s<<<512, 512, 0, stream>>>(u1, ws);
        spline_k2<<<512, 512, 0, stream>>>(u1, ws, (float*)d_out);
    } else {
        prep_f<<<136, 256, 0, stream>>>(W1, W2, W3, b3, ws);
        spline_mega<<<512, 512, 0, stream>>>(u1, u2, cd, b1, b2, ws, (float*)d_out);
    }
}

// Round 9
// 258.097 us; speedup vs baseline: 4.6170x; 4.6170x over previous
//
#include <hip/hip_runtime.h>
#include <hip/hip_bf16.h>

// R9: GEMM3 re-decomposition for latency tolerance. Wave = 2 m-tiles (32 rows)
// x 128 cols/chunk -> each B-fragment feeds 8 MFMAs (was 4); B-load redundancy
// 4x->2x; depth-2 prefetch now spans ~180cyc; all 8 b3p loads batched/chunk.
// rawb layout + spline phase verbatim from R7/R8 (verified).

typedef short bf16x8 __attribute__((ext_vector_type(8)));
typedef float f32x4 __attribute__((ext_vector_type(4)));

// ---- split-path ws layout ----
#define SW3T_B 0           // [4096][128] bf16 = 1048576
#define SW1T_B 1048576     // [128][192]  bf16 = 49152
#define SW2T_B 1097728     // [128][128]  bf16 = 32768
#define SB3P_B 1130496     // [4096] f32  = 16384
#define SH2_B  1146880     // [32768][128] bf16 = 8388608
#define SPLIT_WS_NEED 9535488ULL

// ---- fallback (R5) ws layout ----
#define FW3T_B 0
#define FW1T_B 917504
#define FW2T_B 966656
#define FB3P_B 999424

__device__ __forceinline__ float b2f(unsigned int u) {
    union { float f; unsigned int i; } v; v.i = u << 16; return v.f;
}
__device__ __forceinline__ unsigned short f2b(float f) {
    union { float f; unsigned int i; } v; v.f = f;
    unsigned int x = v.i;
    return (unsigned short)((x + 0x7fffu + ((x >> 16) & 1u)) >> 16);
}
__device__ __forceinline__ float splus(float x) {
    return __logf(1.0f + __expf(x));
}

// ================= split path =================

__global__ __launch_bounds__(256) void prep_s(
    const float* __restrict__ W1, const float* __restrict__ W2,
    const float* __restrict__ W3, const float* __restrict__ b3,
    char* __restrict__ ws)
{
    __shared__ __align__(16) float tbuf[4224];
    const int b = blockIdx.x, t = threadIdx.x;
    if (b < 128) {
        unsigned short* W3T = (unsigned short*)(ws + SW3T_B);
        const int c0 = b * 32;
        #pragma unroll
        for (int i = 0; i < 16; ++i) {
            int idx = i * 256 + t;
            int c = idx & 31, k = idx >> 5;
            unsigned int cg = (unsigned int)(c0 + c);
            unsigned int dim = cg >> 6, p = cg & 63u;
            float v = (p < 49u) ? W3[(size_t)k * 3136 + dim * 49 + p] : 0.0f;
            tbuf[c * 132 + k] = v;
        }
        __syncthreads();
        const int c = t >> 3, kg = (t & 7) * 16;
        unsigned int d[8];
        #pragma unroll
        for (int i = 0; i < 8; ++i) {
            unsigned int lo = f2b(tbuf[c * 132 + kg + 2 * i]);
            unsigned int hi = f2b(tbuf[c * 132 + kg + 2 * i + 1]);
            d[i] = lo | (hi << 16);
        }
        uint4* dst = (uint4*)(W3T + (size_t)(c0 + c) * 128 + kg);
        dst[0] = make_uint4(d[0], d[1], d[2], d[3]);
        dst[1] = make_uint4(d[4], d[5], d[6], d[7]);
    } else if (b < 138) {
        const float* src; unsigned short* dst; int Kdw, tk, tn;
        if (b < 134) { int lb = b - 128; src = W1; dst = (unsigned short*)(ws + SW1T_B); Kdw = 96; tk = lb % 3; tn = lb / 3; }
        else         { int lb = b - 134; src = W2; dst = (unsigned short*)(ws + SW2T_B); Kdw = 64; tk = lb & 1; tn = lb >> 1; }
        const int nl = t & 63, kq = t >> 6;
        #pragma unroll
        for (int i = 0; i < 16; ++i) {
            int kl = i * 4 + kq;
            tbuf[kl * 65 + nl] = src[(size_t)(tk * 64 + kl) * 128 + tn * 64 + nl];
        }
        __syncthreads();
        unsigned int* d32 = (unsigned int*)dst;
        const int kp = t & 31, nq = t >> 5;
        #pragma unroll
        for (int i = 0; i < 8; ++i) {
            int n = i * 8 + nq;
            unsigned int lo = f2b(tbuf[(2 * kp) * 65 + n]);
            unsigned int hi = f2b(tbuf[(2 * kp + 1) * 65 + n]);
            d32[(size_t)(tn * 64 + n) * Kdw + tk * 32 + kp] = lo | (hi << 16);
        }
    } else {
        int c = (b - 138) * 256 + t;
        unsigned int dim = (unsigned int)c >> 6, p = (unsigned int)c & 63u;
        float* b3p = (float*)(ws + SB3P_B);
        b3p[c] = (p < 49u) ? b3[dim * 49 + p] : 0.0f;
    }
}

__global__ __launch_bounds__(512) void mlp_k1(
    const float* __restrict__ u2, const float* __restrict__ cnd,
    const float* __restrict__ b1, const float* __restrict__ b2,
    char* __restrict__ ws)
{
    __shared__ __align__(16) char smem[43008];
    unsigned short* xb  = (unsigned short*)smem;            // [64][200]
    unsigned short* h1b = (unsigned short*)(smem + 25600);  // [64][136]
    unsigned short* h2b = (unsigned short*)smem;            // [64][144]
    const unsigned short* W1T = (const unsigned short*)(ws + SW1T_B);
    const unsigned short* W2T = (const unsigned short*)(ws + SW2T_B);
    unsigned short* H2 = (unsigned short*)(ws + SH2_B);

    const int t = threadIdx.x;
    const int row0 = blockIdx.x * 64;
    const int w = t >> 6, lane = t & 63;
    const int l15 = lane & 15, lg = lane >> 4;

    {
        const float2* u2v = (const float2*)(u2 + (size_t)row0 * 64);
        #pragma unroll
        for (int p = 0; p < 4; ++p) {
            int idx = t + p * 512;
            int r = idx >> 5, c2 = idx & 31;
            float2 v = u2v[idx];
            *(unsigned int*)((char*)xb + r * 400 + c2 * 4) =
                (unsigned int)f2b(v.x) | ((unsigned int)f2b(v.y) << 16);
        }
        const float2* cdv = (const float2*)(cnd + (size_t)row0 * 128);
        #pragma unroll
        for (int p = 0; p < 8; ++p) {
            int idx = t + p * 512;
            int r = idx >> 6, c2 = idx & 63;
            float2 v = cdv[idx];
            *(unsigned int*)((char*)xb + r * 400 + 128 + c2 * 4) =
                (unsigned int)f2b(v.x) | ((unsigned int)f2b(v.y) << 16);
        }
    }
    __syncthreads();

    {
        const int mt = w >> 1;
        bf16x8 af[6];
        #pragma unroll
        for (int kg = 0; kg < 6; ++kg)
            af[kg] = *(const bf16x8*)((char*)xb + (mt * 16 + l15) * 400 + kg * 64 + lg * 16);
        #pragma unroll
        for (int ni = 0; ni < 4; ++ni) {
            int nt = (w & 1) + ni * 2;
            int j = nt * 16 + l15;
            f32x4 acc = {0.f, 0.f, 0.f, 0.f};
            #pragma unroll
            for (int kg = 0; kg < 6; ++kg) {
                bf16x8 bf = *(const bf16x8*)(W1T + (size_t)j * 192 + kg * 32 + lg * 8);
                acc = __builtin_amdgcn_mfma_f32_16x16x32_bf16(af[kg], bf, acc, 0, 0, 0);
            }
            float bj = b1[j];
            #pragma unroll
            for (int r = 0; r < 4; ++r)
                h1b[(mt * 16 + lg * 4 + r) * 136 + j] = f2b(fmaxf(acc[r] + bj, 0.f));
        }
    }
    __syncthreads();

    {
        const int mt = w >> 1;
        bf16x8 af[4];
        #pragma unroll
        for (int kg = 0; kg < 4; ++kg)
            af[kg] = *(const bf16x8*)((char*)h1b + (mt * 16 + l15) * 272 + kg * 64 + lg * 16);
        #pragma unroll
        for (int ni = 0; ni < 4; ++ni) {
            int nt = (w & 1) + ni * 2;
            int j = nt * 16 + l15;
            f32x4 acc = {0.f, 0.f, 0.f, 0.f};
            #pragma unroll
            for (int kg = 0; kg < 4; ++kg) {
                bf16x8 bf = *(const bf16x8*)(W2T + (size_t)j * 128 + kg * 32 + lg * 8);
                acc = __builtin_amdgcn_mfma_f32_16x16x32_bf16(af[kg], bf, acc, 0, 0, 0);
            }
            float bj = b2[j];
            #pragma unroll
            for (int r = 0; r < 4; ++r)
                h2b[(mt * 16 + lg * 4 + r) * 144 + j] = f2b(fmaxf(acc[r] + bj, 0.f));
        }
    }
    __syncthreads();

    {
        int r = t >> 3, cq = t & 7;
        uint4 v0 = *(const uint4*)((char*)h2b + r * 288 + cq * 32);
        uint4 v1 = *(const uint4*)((char*)h2b + r * 288 + cq * 32 + 16);
        uint4* dst = (uint4*)(H2 + ((size_t)(row0 + r) * 128 + cq * 16));
        dst[0] = v0;
        dst[1] = v1;
    }
}

// K2: GEMM3 + spline. Wave = 2 m-tiles x 128 cols/chunk (8 n-tiles), depth-2
// B-prefetch, batched bj. rawb[64][520] + spline verbatim from R8.
__global__ __launch_bounds__(512, 4) void spline_k2(
    const float* __restrict__ u1, const char* __restrict__ ws,
    float* __restrict__ out)
{
    __shared__ __align__(16) unsigned short rawb[64 * 520];
    const unsigned short* W3T = (const unsigned short*)(ws + SW3T_B);
    const float* b3p = (const float*)(ws + SB3P_B);
    const unsigned short* H2 = (const unsigned short*)(ws + SH2_B);

    const int t = threadIdx.x;
    const int row0 = blockIdx.x * 64;
    const int w = t >> 6, lane = t & 63;
    const int l15 = lane & 15, lg = lane >> 4;
    const int mhalf = w & 1, ng2 = w >> 1;     // 2 m-tiles/wave, 4 col-groups
    const int lrow = t >> 3, dsl = t & 7;

    // A fragments for both m-tiles, once, from global h2
    bf16x8 a3[2][4];
    #pragma unroll
    for (int mi = 0; mi < 2; ++mi)
        #pragma unroll
        for (int kg = 0; kg < 4; ++kg)
            a3[mi][kg] = *(const bf16x8*)(H2 +
                ((size_t)(row0 + (mhalf * 2 + mi) * 16 + l15) * 128 + kg * 32 + lg * 8));

    const float XS = logf(expm1f(0.625f));
    const float DS = logf(expm1f(1.0f));
    float lja = 0.f;

    #pragma unroll 1
    for (int dc = 0; dc < 8; ++dc) {
        const float tv = u1[(size_t)(row0 + lrow) * 64 + dc * 8 + dsl];

        // ---- GEMM chunk: this wave covers n-tiles [ng2*8, ng2*8+8), m-tiles {2*mhalf, 2*mhalf+1} ----
        {
            const int ntb = ng2 * 8;
            float bjv[8];
            #pragma unroll
            for (int j = 0; j < 8; ++j)
                bjv[j] = b3p[dc * 512 + (ntb + j) * 16 + l15];
            bf16x8 bfb[2][4];
            #pragma unroll
            for (int kg = 0; kg < 4; ++kg) {
                bfb[0][kg] = *(const bf16x8*)(W3T + (size_t)(dc * 512 + ntb * 16 + l15) * 128 + kg * 32 + lg * 8);
                bfb[1][kg] = *(const bf16x8*)(W3T + (size_t)(dc * 512 + (ntb + 1) * 16 + l15) * 128 + kg * 32 + lg * 8);
            }
            #pragma unroll
            for (int j = 0; j < 8; ++j) {
                const int cur = j & 1;
                f32x4 e0[2], e1[2];
                #pragma unroll
                for (int mi = 0; mi < 2; ++mi) {
                    e0[mi] = {0.f, 0.f, 0.f, 0.f};
                    e1[mi] = {0.f, 0.f, 0.f, 0.f};
                    e0[mi] = __builtin_amdgcn_mfma_f32_16x16x32_bf16(a3[mi][0], bfb[cur][0], e0[mi], 0, 0, 0);
                    e1[mi] = __builtin_amdgcn_mfma_f32_16x16x32_bf16(a3[mi][1], bfb[cur][1], e1[mi], 0, 0, 0);
                    e0[mi] = __builtin_amdgcn_mfma_f32_16x16x32_bf16(a3[mi][2], bfb[cur][2], e0[mi], 0, 0, 0);
                    e1[mi] = __builtin_amdgcn_mfma_f32_16x16x32_bf16(a3[mi][3], bfb[cur][3], e1[mi], 0, 0, 0);
                }
                if (j + 2 < 8) {
                    #pragma unroll
                    for (int kg = 0; kg < 4; ++kg)
                        bfb[cur][kg] = *(const bf16x8*)(W3T +
                            (size_t)(dc * 512 + (ntb + j + 2) * 16 + l15) * 128 + kg * 32 + lg * 8);
                }
                const int c = (ntb + j) * 16 + l15;
                const int coff = ((c >> 3) & 7) * 64 + (c >> 6) * 8 + (c & 7);
                #pragma unroll
                for (int mi = 0; mi < 2; ++mi)
                    #pragma unroll
                    for (int r = 0; r < 4; ++r)
                        rawb[((mhalf * 2 + mi) * 16 + lg * 4 + r) * 520 + coff] =
                            f2b(e0[mi][r] + e1[mi][r] + bjv[j]);
            }
        }
        __syncthreads();

        // ---- spline: 512 tasks = 64 rows x 8 dims (verbatim R8) ----
        {
            union { uint4 q[7]; unsigned short s[56]; } P;
            const uint4* pq = (const uint4*)(rawb + lrow * 520 + dsl * 8);
            #pragma unroll
            for (int i = 0; i < 7; ++i) P.q[i] = pq[i * 8];

            const float left   = b2f(P.s[0]) - 5.0f;
            const float bottom = b2f(P.s[1]) - 5.0f;
            float wv[16], hv[16];
            float wsum = 0.f, hsum = 0.f;
            #pragma unroll
            for (int i = 0; i < 16; ++i) { wv[i] = splus(b2f(P.s[2 + i])  + XS); wsum += wv[i]; }
            #pragma unroll
            for (int i = 0; i < 16; ++i) { hv[i] = splus(b2f(P.s[18 + i]) + XS); hsum += hv[i]; }
            const float scale = hsum / wsum;
            float kx = left; int cnt = (kx < tv) ? 1 : 0;
            #pragma unroll
            for (int i = 0; i < 16; ++i) { kx += wv[i]; cnt += (kx < tv) ? 1 : 0; }
            const bool indom = (left < tv) && (tv <= kx);
            const int hi = min(max(cnt, 1), 16);
            const int lo = hi - 1;
            float xk = 0.f, xkp = 0.f, yk = 0.f, ykp = 0.f;
            float cx = left, cy = bottom;
            #pragma unroll
            for (int i = 0; i < 16; ++i) {
                float nx = cx + wv[i], ny = cy + hv[i];
                if (i == lo) { xk = cx; xkp = nx; yk = cy; ykp = ny; }
                cx = nx; cy = ny;
            }
            const int pl = 33 + lo, ph = 33 + hi;
            const float dk  = (lo == 0)
                ? scale : splus(b2f(rawb[lrow * 520 + (pl >> 3) * 64 + dsl * 8 + (pl & 7)]) + DS);
            const float dkp = (hi == 16)
                ? scale : splus(b2f(rawb[lrow * 520 + (ph >> 3) * 64 + dsl * 8 + (ph & 7)]) + DS);
            const float dxk = xkp - xk, dyk = ykp - yk;
            const float sk = dyk / dxk;
            float xi = (tv - xk) / dxk;
            xi = fminf(fmaxf(xi, 0.f), 1.f);
            const float om = 1.f - xi;
            const float num = dyk * (sk * xi * xi + dk * xi * om);
            const float den = sk + (dkp + dk - 2.f * sk) * xi * om;
            const float resin = yk + num / den;
            const float jn = sk * sk * (dkp * xi * xi + 2.f * sk * xi * om + dk * om * om);
            const float ljin = __logf(jn + 1e-10f) - __logf(den * den + 1e-10f);
            const float resout = scale * tv + (bottom - scale * left);
            const float ljout = __logf(scale + 1e-10f);
            out[(size_t)(row0 + lrow) * 64 + dc * 8 + dsl] = indom ? resin : resout;
            lja += indom ? ljin : ljout;
        }
        __syncthreads();
    }

    float lj = lja;
    lj += __shfl_xor(lj, 1, 64);
    lj += __shfl_xor(lj, 2, 64);
    lj += __shfl_xor(lj, 4, 64);
    if (dsl == 0) out[(size_t)32768 * 64 + row0 + lrow] = lj;
}

// ================= fallback path (R5, verbatim) =================

__global__ __launch_bounds__(256) void prep_f(
    const float* __restrict__ W1, const float* __restrict__ W2,
    const float* __restrict__ W3, const float* __restrict__ b3,
    char* __restrict__ ws)
{
    __shared__ __align__(16) float tbuf[4224];
    const int b = blockIdx.x, t = threadIdx.x;
    if (b < 112) {
        unsigned short* W3T = (unsigned short*)(ws + FW3T_B);
        const int c0 = b * 32;
        #pragma unroll
        for (int i = 0; i < 16; ++i) {
            int idx = i * 256 + t;
            int c = idx & 31, k = idx >> 5;
            unsigned int cg = (unsigned int)(c0 + c);
            unsigned int dim = cg / 56u, p = cg % 56u;
            float v = (p < 49u) ? W3[(size_t)k * 3136 + dim * 49 + p] : 0.0f;
            tbuf[c * 132 + k] = v;
        }
        __syncthreads();
        const int c = t >> 3, kg = (t & 7) * 16;
        unsigned int d[8];
        #pragma unroll
        for (int i = 0; i < 8; ++i) {
            unsigned int lo = f2b(tbuf[c * 132 + kg + 2 * i]);
            unsigned int hi = f2b(tbuf[c * 132 + kg + 2 * i + 1]);
            d[i] = lo | (hi << 16);
        }
        uint4* dst = (uint4*)(W3T + (size_t)(c0 + c) * 128 + kg);
        dst[0] = make_uint4(d[0], d[1], d[2], d[3]);
        dst[1] = make_uint4(d[4], d[5], d[6], d[7]);
    } else if (b < 122) {
        const float* src; unsigned short* dst; int Kdw, tk, tn;
        if (b < 118) { int lb = b - 112; src = W1; dst = (unsigned short*)(ws + FW1T_B); Kdw = 96; tk = lb % 3; tn = lb / 3; }
        else         { int lb = b - 118; src = W2; dst = (unsigned short*)(ws + FW2T_B); Kdw = 64; tk = lb & 1; tn = lb >> 1; }
        const int nl = t & 63, kq = t >> 6;
        #pragma unroll
        for (int i = 0; i < 16; ++i) {
            int kl = i * 4 + kq;
            tbuf[kl * 65 + nl] = src[(size_t)(tk * 64 + kl) * 128 + tn * 64 + nl];
        }
        __syncthreads();
        unsigned int* d32 = (unsigned int*)dst;
        const int kp = t & 31, nq = t >> 5;
        #pragma unroll
        for (int i = 0; i < 8; ++i) {
            int n = i * 8 + nq;
            unsigned int lo = f2b(tbuf[(2 * kp) * 65 + n]);
            unsigned int hi = f2b(tbuf[(2 * kp + 1) * 65 + n]);
            d32[(size_t)(tn * 64 + n) * Kdw + tk * 32 + kp] = lo | (hi << 16);
        }
    } else {
        int c = (b - 122) * 256 + t;
        unsigned int dim = (unsigned int)c / 56u, p = (unsigned int)c % 56u;
        float* b3p = (float*)(ws + FB3P_B);
        b3p[c] = (p < 49u) ? b3[dim * 49 + p] : 0.0f;
    }
}

__global__ __launch_bounds__(512, 4) void spline_mega(
    const float* __restrict__ u1, const float* __restrict__ u2,
    const float* __restrict__ cnd, const float* __restrict__ b1,
    const float* __restrict__ b2, const char* __restrict__ ws,
    float* __restrict__ out)
{
    __shared__ __align__(16) char smem[75776];
    unsigned short* h2b  = (unsigned short*)smem;
    unsigned short* xb   = (unsigned short*)(smem + 17408);
    unsigned short* h1b  = (unsigned short*)(smem + 43008);
    unsigned short* rawb = (unsigned short*)(smem + 17408);
    const unsigned short* W3T = (const unsigned short*)(ws + FW3T_B);
    const unsigned short* W1T = (const unsigned short*)(ws + FW1T_B);
    const unsigned short* W2T = (const unsigned short*)(ws + FW2T_B);
    const float* b3p = (const float*)(ws + FB3P_B);

    const int t = threadIdx.x;
    const int row0 = blockIdx.x * 64;
    const int w = t >> 6, lane = t & 63;
    const int l15 = lane & 15, lg = lane >> 4;

    {
        const float2* u2v = (const float2*)(u2 + (size_t)row0 * 64);
        #pragma unroll
        for (int p = 0; p < 4; ++p) {
            int idx = t + p * 512;
            int r = idx >> 5, c2 = idx & 31;
            float2 v = u2v[idx];
            *(unsigned int*)((char*)xb + r * 400 + c2 * 4) =
                (unsigned int)f2b(v.x) | ((unsigned int)f2b(v.y) << 16);
        }
        const float2* cdv = (const float2*)(cnd + (size_t)row0 * 128);
        #pragma unroll
        for (int p = 0; p < 8; ++p) {
            int idx = t + p * 512;
            int r = idx >> 6, c2 = idx & 63;
            float2 v = cdv[idx];
            *(unsigned int*)((char*)xb + r * 400 + 128 + c2 * 4) =
                (unsigned int)f2b(v.x) | ((unsigned int)f2b(v.y) << 16);
        }
    }
    __syncthreads();

    {
        const int mt = w >> 1;
        bf16x8 af[6];
        #pragma unroll
        for (int kg = 0; kg < 6; ++kg)
            af[kg] = *(const bf16x8*)((char*)xb + (mt * 16 + l15) * 400 + kg * 64 + lg * 16);
        #pragma unroll
        for (int ni = 0; ni < 4; ++ni) {
            int nt = (w & 1) + ni * 2;
            int j = nt * 16 + l15;
            f32x4 acc = {0.f, 0.f, 0.f, 0.f};
            #pragma unroll
            for (int kg = 0; kg < 6; ++kg) {
                bf16x8 bf = *(const bf16x8*)(W1T + (size_t)j * 192 + kg * 32 + lg * 8);
                acc = __builtin_amdgcn_mfma_f32_16x16x32_bf16(af[kg], bf, acc, 0, 0, 0);
            }
            float bj = b1[j];
            #pragma unroll
            for (int r = 0; r < 4; ++r)
                h1b[(mt * 16 + lg * 4 + r) * 136 + j] = f2b(fmaxf(acc[r] + bj, 0.f));
        }
    }
    __syncthreads();

    {
        const int mt = w >> 1;
        bf16x8 af[4];
        #pragma unroll
        for (int kg = 0; kg < 4; ++kg)
            af[kg] = *(const bf16x8*)((char*)h1b + (mt * 16 + l15) * 272 + kg * 64 + lg * 16);
        #pragma unroll
        for (int ni = 0; ni < 4; ++ni) {
            int nt = (w & 1) + ni * 2;
            int j = nt * 16 + l15;
            f32x4 acc = {0.f, 0.f, 0.f, 0.f};
            #pragma unroll
            for (int kg = 0; kg < 4; ++kg) {
                bf16x8 bf = *(const bf16x8*)(W2T + (size_t)j * 128 + kg * 32 + lg * 8);
                acc = __builtin_amdgcn_mfma_f32_16x16x32_bf16(af[kg], bf, acc, 0, 0, 0);
            }
            float bj = b2[j];
            #pragma unroll
            for (int r = 0; r < 4; ++r)
                h2b[(mt * 16 + lg * 4 + r) * 136 + j] = f2b(fmaxf(acc[r] + bj, 0.f));
        }
    }
    __syncthreads();

    const float XS = logf(expm1f(0.625f));
    const float DS = logf(expm1f(1.0f));

    const int mt3 = w & 3, ng = w >> 2;
    bf16x8 a3[4];
    #pragma unroll
    for (int kg = 0; kg < 4; ++kg)
        a3[kg] = *(const bf16x8*)((char*)h2b + (mt3 * 16 + l15) * 272 + kg * 64 + lg * 16);
    const int lrow = t >> 3, dsl = t & 7;
    float lja = 0.f;

    for (int dc = 0; dc < 8; ++dc) {
        const float tv = u1[(size_t)(row0 + lrow) * 64 + dc * 8 + dsl];
        {
            bf16x8 bf0[4];
            {
                int colg = dc * 448 + ng * 16 + l15;
                #pragma unroll
                for (int kg = 0; kg < 4; ++kg)
                    bf0[kg] = *(const bf16x8*)(W3T + (size_t)colg * 128 + kg * 32 + lg * 8);
            }
            for (int nt = ng; nt < 28; nt += 2) {
                int colg = dc * 448 + nt * 16 + l15;
                bf16x8 bf1[4];
                if (nt + 2 < 28) {
                    #pragma unroll
                    for (int kg = 0; kg < 4; ++kg)
                        bf1[kg] = *(const bf16x8*)(W3T + (size_t)(colg + 32) * 128 + kg * 32 + lg * 8);
                }
                float bj = b3p[colg];
                f32x4 acc0 = {0.f, 0.f, 0.f, 0.f}, acc1 = {0.f, 0.f, 0.f, 0.f};
                acc0 = __builtin_amdgcn_mfma_f32_16x16x32_bf16(a3[0], bf0[0], acc0, 0, 0, 0);
                acc1 = __builtin_amdgcn_mfma_f32_16x16x32_bf16(a3[1], bf0[1], acc1, 0, 0, 0);
                acc0 = __builtin_amdgcn_mfma_f32_16x16x32_bf16(a3[2], bf0[2], acc0, 0, 0, 0);
                acc1 = __builtin_amdgcn_mfma_f32_16x16x32_bf16(a3[3], bf0[3], acc1, 0, 0, 0);
                #pragma unroll
                for (int r = 0; r < 4; ++r)
                    rawb[(mt3 * 16 + lg * 4 + r) * 456 + nt * 16 + l15] =
                        f2b(acc0[r] + acc1[r] + bj);
                #pragma unroll
                for (int kg = 0; kg < 4; ++kg) bf0[kg] = bf1[kg];
            }
        }
        __syncthreads();
        {
            union { uint4 q[7]; unsigned short s[56]; } P;
            const uint4* pq = (const uint4*)(rawb + lrow * 456 + dsl * 56);
            #pragma unroll
            for (int i = 0; i < 7; ++i) P.q[i] = pq[i];

            const float left   = b2f(P.s[0]) - 5.0f;
            const float bottom = b2f(P.s[1]) - 5.0f;
            float wv[16], hv[16];
            float wsum = 0.f, hsum = 0.f;
            #pragma unroll
            for (int i = 0; i < 16; ++i) { wv[i] = splus(b2f(P.s[2 + i])  + XS); wsum += wv[i]; }
            #pragma unroll
            for (int i = 0; i < 16; ++i) { hv[i] = splus(b2f(P.s[18 + i]) + XS); hsum += hv[i]; }
            const float scale = hsum / wsum;
            float kx = left; int cnt = (kx < tv) ? 1 : 0;
            #pragma unroll
            for (int i = 0; i < 16; ++i) { kx += wv[i]; cnt += (kx < tv) ? 1 : 0; }
            const bool indom = (left < tv) && (tv <= kx);
            const int hi = min(max(cnt, 1), 16);
            const int lo = hi - 1;
            float xk = 0.f, xkp = 0.f, yk = 0.f, ykp = 0.f;
            float cx = left, cy = bottom;
            #pragma unroll
            for (int i = 0; i < 16; ++i) {
                float nx = cx + wv[i], ny = cy + hv[i];
                if (i == lo) { xk = cx; xkp = nx; yk = cy; ykp = ny; }
                cx = nx; cy = ny;
            }
            const unsigned short* prd = rawb + lrow * 456 + dsl * 56;
            const float dk  = (lo == 0)  ? scale : splus(b2f(prd[33 + lo]) + DS);
            const float dkp = (hi == 16) ? scale : splus(b2f(prd[33 + hi]) + DS);
            const float dxk = xkp - xk, dyk = ykp - yk;
            const float sk = dyk / dxk;
            float xi = (tv - xk) / dxk;
            xi = fminf(fmaxf(xi, 0.f), 1.f);
            const float om = 1.f - xi;
            const float num = dyk * (sk * xi * xi + dk * xi * om);
            const float den = sk + (dkp + dk - 2.f * sk) * xi * om;
            const float resin = yk + num / den;
            const float jn = sk * sk * (dkp * xi * xi + 2.f * sk * xi * om + dk * om * om);
            const float ljin = __logf(jn + 1e-10f) - __logf(den * den + 1e-10f);
            const float resout = scale * tv + (bottom - scale * left);
            const float ljout = __logf(scale + 1e-10f);
            out[(size_t)(row0 + lrow) * 64 + dc * 8 + dsl] = indom ? resin : resout;
            lja += indom ? ljin : ljout;
        }
        __syncthreads();
    }

    float lj = lja;
    lj += __shfl_xor(lj, 1, 64);
    lj += __shfl_xor(lj, 2, 64);
    lj += __shfl_xor(lj, 4, 64);
    if (dsl == 0) out[(size_t)32768 * 64 + row0 + lrow] = lj;
}

extern "C" void kernel_launch(void* const* d_in, const int* in_sizes, int n_in,
                              void* d_out, int out_size, void* d_ws, size_t ws_size,
                              hipStream_t stream) {
    const float* u1 = (const float*)d_in[0];
    const float* u2 = (const float*)d_in[1];
    const float* cd = (const float*)d_in[2];
    const float* W1 = (const float*)d_in[3];
    const float* b1 = (const float*)d_in[4];
    const float* W2 = (const float*)d_in[5];
    const float* b2 = (const float*)d_in[6];
    const float* W3 = (const float*)d_in[7];
    const float* b3 = (const float*)d_in[8];
    char* ws = (char*)d_ws;
    if (ws_size >= SPLIT_WS_NEED) {
        prep_s<<<154, 256, 0, stream>>>(W1, W2, W3, b3, ws);
        mlp_k1<<<512, 512, 0, stream>>>(u2, cd, b1, b2, ws);
        spline_k2<<<512, 512, 0, stream>>>(u1, ws, (float*)d_out);
    } else {
        prep_f<<<136, 256, 0, stream>>>(W1, W2, W3, b3, ws);
        spline_mega<<<512, 512, 0, stream>>>(u1, u2, cd, b1, b2, ws, (float*)d_out);
    }
}